// Round 1
// baseline (390.759 us; speedup 1.0000x reference)
//
// R8: gemm restructure. k_sum / k_fam / k_sample / PRNG byte-identical to R7.
// k_gemm: (1) atomicAdd epilogue (16.8M RMW dwords, WRITE_SIZE=64MB) replaced by
// non-atomic split-K partials + k_reduce (runtime fallback to atomics if ws too
// small); (2) 512-thr / 8-wave blocks, full 256-row A tile, wave tile 32x128
// (acc[2][8]) -> MFMA:ds_read ratio 2.7:1; (3) register-prefetch pipeline
// (loads for st+1 issued before MFMA of st); (4) XOR bank swizzle P=L^((L>>3)&7)
// on both LDS tiles, both sides; (5) bid encode keeps same-chunk blocks on one XCD.
#include <hip/hip_runtime.h>
#include <stdint.h>

#define BATCH 256
#define NMAC  512
#define ROWF  128            // cms_prev * neur_prev
#define I_    32768
#define C_    32
#define N_    32
#define XROW  (NMAC * ROWF)  // 65536 floats per batch row
#define NCH   64             // split-K chunks (512 i each)
#define NST   16             // stages per chunk (KK=32)

typedef float  f32x4  __attribute__((ext_vector_type(4)));
typedef __bf16 bf16x8 __attribute__((ext_vector_type(8)));

__device__ __forceinline__ uint32_t f2bf_rne(float f) {
    uint32_t u = __builtin_bit_cast(uint32_t, f);
    return (u + 0x7FFFu + ((u >> 16) & 1u)) >> 16;
}

// ---------------- per-row sums S[b] (unchanged from R7) ----------------
__global__ __launch_bounds__(256) void k_sum(const float* __restrict__ x,
                                             const int* __restrict__ filt,
                                             float* __restrict__ S) {
    const int b = blockIdx.x;
    const int t = threadIdx.x;
    const float* xb = x + (size_t)b * XROW;
    float s = 0.f;
    for (int it = 0; it < 32; ++it) {
        int idx4 = it * 256 + t;           // 8192 float4 in gathered row
        int f = idx4 >> 5;
        int j4 = idx4 & 31;
        float4 v = *(const float4*)(xb + (size_t)filt[f] * ROWF + j4 * 4);
        s += v.x + v.y + v.z + v.w;
    }
    for (int o = 32; o > 0; o >>= 1) s += __shfl_down(s, o, 64);
    __shared__ float red[4];
    if ((t & 63) == 0) red[t >> 6] = s;
    __syncthreads();
    if (t == 0) S[b] = red[0] + red[1] + red[2] + red[3];
}

// ---------------- split-K GEMM: part[chunk][b][c][n] (or atomic fallback) ----
// grid = 512: chunk = bid&63 (512 i each), cg = bid>>6 (4 c each).
// 512 thr / 8 waves; A tile 256x32 fp32 -> hi/lo bf16 (32 KB LDS),
// W tile 4c x 32k x 32n bf16 (8 KB). Wave tile: 2 row-tiles x 8 ct, acc[2][8].
__global__ __launch_bounds__(512, 4) void k_gemm(const float* __restrict__ x,
                                                 const int* __restrict__ filt,
                                                 const float* __restrict__ w,
                                                 float* __restrict__ part,
                                                 float* __restrict__ raw,
                                                 int use_part) {
    __shared__ __align__(16) unsigned short afr[32 * 512];  // [rt 16][p 2][512] 32 KB
    __shared__ __align__(16) unsigned short wfr[8 * 512];   // [ct 8][512]        8 KB

    const int t  = threadIdx.x;
    const int l  = t & 63;
    const int wv = t >> 6;
    const int chunk = blockIdx.x & 63;
    const int c0 = (blockIdx.x >> 6) * 4;

    // A staging map: 2 threads per row, interleaved float4 slots ai = akq + 2*jj
    const int arow = t >> 1;             // 0..255
    const int akq  = t & 1;
    const int r15  = arow & 15;
    const int rt_a = arow >> 4;          // 0..15
    const float* xr = x + (size_t)arow * XROW + akq * 4;

    // W staging map: 2 k-quads per thread
    const int wn  = t & 31;
    const int wsl = t >> 5;              // 0..15

    f32x4 acc0[8], acc1[8];
#pragma unroll
    for (int i = 0; i < 8; ++i) {
        acc0[i] = f32x4{0.f, 0.f, 0.f, 0.f};
        acc1[i] = f32x4{0.f, 0.f, 0.f, 0.f};
    }

    auto loadA = [&](int st, float4* A) {
        const int ifull = chunk * 512 + st * 32;
        const int fidx  = filt[ifull >> 7];
        const float* pa = xr + (size_t)fidx * ROWF + (ifull & 127);
#pragma unroll
        for (int jj = 0; jj < 4; ++jj)      // k = (akq + 2*jj)*4 .. +3
            A[jj] = *(const float4*)(pa + jj * 8);
    };

    auto loadW = [&](int st, uint2* W) {    // pack to bf16 at load ({0,1} exact)
        const int ifull = chunk * 512 + st * 32;
#pragma unroll
        for (int q = 0; q < 2; ++q) {
            int sl = wsl + 16 * q;          // 0..31 = (c, k-quad)
            int c  = sl >> 3;
            int kk = (sl & 7) * 4;          // 0..28
            const float* wp = w + ((size_t)(c0 + c) * I_ + ifull + kk) * N_ + wn;
            uint32_t u0 = __builtin_bit_cast(uint32_t, wp[0]);
            uint32_t u1 = __builtin_bit_cast(uint32_t, wp[N_]);
            uint32_t u2 = __builtin_bit_cast(uint32_t, wp[2 * N_]);
            uint32_t u3 = __builtin_bit_cast(uint32_t, wp[3 * N_]);
            W[q].x = (u0 >> 16) | (u1 & 0xFFFF0000u);
            W[q].y = (u2 >> 16) | (u3 & 0xFFFF0000u);
        }
    };

    auto storeW = [&](const uint2* W) {
#pragma unroll
        for (int q = 0; q < 2; ++q) {
            int sl = wsl + 16 * q;
            int c  = sl >> 3;
            int kk = (sl & 7) * 4;
            int L  = ((kk >> 3) << 4) + (wn & 15);
            int P  = L ^ ((L >> 3) & 7);               // bank swizzle
            int ct = c * 2 + (wn >> 4);
            *(uint2*)&wfr[ct * 512 + P * 8 + (kk & 4)] = W[q];
        }
    };

    auto storeA = [&](const float4* A) {
#pragma unroll
        for (int jj = 0; jj < 4; ++jj) {
            float4 v = A[jj];
            int k0 = (akq + 2 * jj) * 4;
            int L  = ((k0 >> 3) << 4) + r15;
            int P  = L ^ ((L >> 3) & 7);               // bank swizzle
            uint32_t u0 = __builtin_bit_cast(uint32_t, v.x);
            uint32_t u1 = __builtin_bit_cast(uint32_t, v.y);
            uint32_t u2 = __builtin_bit_cast(uint32_t, v.z);
            uint32_t u3 = __builtin_bit_cast(uint32_t, v.w);
            // hi = truncate-to-bf16; lo = RNE bf16 of remainder (exact-enough pair)
            float l0 = v.x - __builtin_bit_cast(float, u0 & 0xFFFF0000u);
            float l1 = v.y - __builtin_bit_cast(float, u1 & 0xFFFF0000u);
            float l2 = v.z - __builtin_bit_cast(float, u2 & 0xFFFF0000u);
            float l3 = v.w - __builtin_bit_cast(float, u3 & 0xFFFF0000u);
            uint2 hp, lp;
            hp.x = (u0 >> 16) | (u1 & 0xFFFF0000u);
            hp.y = (u2 >> 16) | (u3 & 0xFFFF0000u);
            lp.x = f2bf_rne(l0) | (f2bf_rne(l1) << 16);
            lp.y = f2bf_rne(l2) | (f2bf_rne(l3) << 16);
            int base = (rt_a * 2) * 512 + P * 8 + (k0 & 4);
            *(uint2*)&afr[base]       = hp;            // part 0 (hi)
            *(uint2*)&afr[base + 512] = lp;            // part 1 (lo)
        }
    };

    const int Pl8 = (l ^ ((l >> 3) & 7)) * 8;
    auto MM = [&]() {
        const int rt0 = wv * 2, rt1 = rt0 + 1;
        bf16x8 a00 = *(const bf16x8*)&afr[(rt0 * 2 + 0) * 512 + Pl8];
        bf16x8 a01 = *(const bf16x8*)&afr[(rt0 * 2 + 1) * 512 + Pl8];
        bf16x8 a10 = *(const bf16x8*)&afr[(rt1 * 2 + 0) * 512 + Pl8];
        bf16x8 a11 = *(const bf16x8*)&afr[(rt1 * 2 + 1) * 512 + Pl8];
#pragma unroll
        for (int i = 0; i < 8; ++i) {
            bf16x8 b = *(const bf16x8*)&wfr[i * 512 + Pl8];
            acc0[i] = __builtin_amdgcn_mfma_f32_16x16x32_bf16(a00, b, acc0[i], 0, 0, 0);
            acc0[i] = __builtin_amdgcn_mfma_f32_16x16x32_bf16(a01, b, acc0[i], 0, 0, 0);
            acc1[i] = __builtin_amdgcn_mfma_f32_16x16x32_bf16(a10, b, acc1[i], 0, 0, 0);
            acc1[i] = __builtin_amdgcn_mfma_f32_16x16x32_bf16(a11, b, acc1[i], 0, 0, 0);
        }
    };

    float4 Aa[4], Ab[4];
    uint2  Wa[2], Wb[2];
    loadA(0, Aa); loadW(0, Wa);
    for (int st = 0; st < NST; st += 2) {
        if (st) __syncthreads();           // prev MFMA reads done
        storeA(Aa); storeW(Wa);
        loadA(st + 1, Ab); loadW(st + 1, Wb);   // in flight across MFMA
        __syncthreads();
        MM();
        __syncthreads();
        storeA(Ab); storeW(Wb);
        if (st + 2 < NST) { loadA(st + 2, Aa); loadW(st + 2, Wa); }
        __syncthreads();
        MM();
    }

    // ---- epilogue: D col = lane&15, row = (lane>>4)*4 + reg (layout as R7) ----
    const int quad = l >> 4, n15 = l & 15;
    float* dst = use_part ? (part + (size_t)chunk * (BATCH * C_ * N_)) : raw;
#pragma unroll
    for (int rr = 0; rr < 2; ++rr) {
        const f32x4* ac = rr ? acc1 : acc0;
        const int bbase = (wv * 2 + rr) * 16 + quad * 4;
#pragma unroll
        for (int i = 0; i < 8; ++i) {
            int c = c0 + (i >> 1);
            int n = (i & 1) * 16 + n15;
#pragma unroll
            for (int r = 0; r < 4; ++r) {
                size_t idx = ((size_t)(bbase + r) * C_ + c) * N_ + n;
                if (use_part) dst[idx] = ac[i][r];
                else          atomicAdd(&dst[idx], ac[i][r]);
            }
        }
    }
}

// ---------------- split-K reduction: raw = sum_ch part[ch] ----------------
__global__ __launch_bounds__(256) void k_reduce(const float* __restrict__ part,
                                                float* __restrict__ raw) {
    const int i4 = blockIdx.x * 256 + threadIdx.x;     // 65536 float4
    const f32x4* p = (const f32x4*)part;
    f32x4 s = f32x4{0.f, 0.f, 0.f, 0.f};
#pragma unroll 8
    for (int ch = 0; ch < NCH; ++ch) s += p[(size_t)ch * 65536 + i4];
    ((f32x4*)raw)[i4] = s;
}

// ---------------- familiarity: fam += max_n(raw)/S per (b,c) (unchanged) -----
__global__ __launch_bounds__(256) void k_fam(const float* __restrict__ raw,
                                             const float* __restrict__ S,
                                             float* __restrict__ fam) {
    int r = blockIdx.x * 256 + threadIdx.x;            // 8192 rows
    const float4* ap = (const float4*)(raw + (size_t)r * N_);
    float m = -3.0e38f;
#pragma unroll
    for (int q = 0; q < 8; ++q) {
        float4 v = ap[q];
        m = fmaxf(m, fmaxf(fmaxf(v.x, v.y), fmaxf(v.z, v.w)));
    }
    m = m / S[r >> 5];                                 // divide after max: monotone-exact
    for (int o = 32; o > 0; o >>= 1) m += __shfl_down(m, o, 64);
    __shared__ float red[4];
    if ((threadIdx.x & 63) == 0) red[threadIdx.x >> 6] = m;
    __syncthreads();
    if (threadIdx.x == 0) atomicAdd(fam, red[0] + red[1] + red[2] + red[3]);
}

// ---------------- Threefry-2x32-20 core (unchanged) ----------------
__device__ __forceinline__ uint32_t rotl32(uint32_t x, uint32_t r) {
    return (x << r) | (x >> (32u - r));
}
__device__ __forceinline__ void threefry(uint32_t k0, uint32_t k1,
                                         uint32_t x0, uint32_t x1,
                                         uint32_t& o0, uint32_t& o1) {
    uint32_t ks2 = k0 ^ k1 ^ 0x1BD11BDAu;
    x0 += k0; x1 += k1;
    x0 += x1; x1 = rotl32(x1, 13); x1 ^= x0;
    x0 += x1; x1 = rotl32(x1, 15); x1 ^= x0;
    x0 += x1; x1 = rotl32(x1, 26); x1 ^= x0;
    x0 += x1; x1 = rotl32(x1, 6);  x1 ^= x0;
    x0 += k1; x1 += ks2 + 1u;
    x0 += x1; x1 = rotl32(x1, 17); x1 ^= x0;
    x0 += x1; x1 = rotl32(x1, 29); x1 ^= x0;
    x0 += x1; x1 = rotl32(x1, 16); x1 ^= x0;
    x0 += x1; x1 = rotl32(x1, 24); x1 ^= x0;
    x0 += ks2; x1 += k0 + 2u;
    x0 += x1; x1 = rotl32(x1, 13); x1 ^= x0;
    x0 += x1; x1 = rotl32(x1, 15); x1 ^= x0;
    x0 += x1; x1 = rotl32(x1, 26); x1 ^= x0;
    x0 += x1; x1 = rotl32(x1, 6);  x1 ^= x0;
    x0 += k0; x1 += k1 + 3u;
    x0 += x1; x1 = rotl32(x1, 17); x1 ^= x0;
    x0 += x1; x1 = rotl32(x1, 29); x1 ^= x0;
    x0 += x1; x1 = rotl32(x1, 16); x1 ^= x0;
    x0 += x1; x1 = rotl32(x1, 24); x1 ^= x0;
    x0 += k1; x1 += ks2 + 4u;
    x0 += x1; x1 = rotl32(x1, 13); x1 ^= x0;
    x0 += x1; x1 = rotl32(x1, 15); x1 ^= x0;
    x0 += x1; x1 = rotl32(x1, 26); x1 ^= x0;
    x0 += x1; x1 = rotl32(x1, 6);  x1 ^= x0;
    x0 += ks2; x1 += k0 + 5u;
    o0 = x0; o1 = x1;
}

__device__ __forceinline__ float gumbel_of(uint32_t bits) {
    uint32_t fb = (bits >> 9) | 0x3F800000u;
    float f = __builtin_bit_cast(float, fb) - 1.0f;
    float u = f + 1.17549435e-38f;                     // == max(tiny, f*(1-tiny)+tiny)
    return -logf(-logf(u));
}

// ---------------- sample (unchanged: JAX partitionable threefry layout) ------
__global__ __launch_bounds__(256) void k_sample(const float* __restrict__ raw,
                                                const float* __restrict__ S,
                                                const float* __restrict__ fam,
                                                int* __restrict__ out) {
    int r0 = blockIdx.x * 256 + threadIdx.x;           // 0..4095
    int r1 = r0 + 4096;
    float avg  = fam[0] * (1.0f / 8192.0f);
    float temp = 1.0f / (avg + 1e-4f) - 1.0f;
    float sA = S[r0 >> 5], sB = S[r1 >> 5];
    const float* apA = raw + (size_t)r0 * N_;
    const float* apB = raw + (size_t)r1 * N_;

    float bestA = -3.4e38f, bestB = -3.4e38f;
    int biA = 0, biB = 0;
    for (int n = 0; n < 32; ++n) {
        uint32_t iA = (uint32_t)(r0 * 32 + n);
        uint32_t iB = (uint32_t)(r1 * 32 + n);
        uint32_t a0, a1, b0, b1;
        threefry(0u, 42u, 0u, iA, a0, a1);
        threefry(0u, 42u, 0u, iB, b0, b1);
        float vA = (apA[n] / sA) / temp + gumbel_of(a0 ^ a1);
        float vB = (apB[n] / sB) / temp + gumbel_of(b0 ^ b1);
        if (vA > bestA) { bestA = vA; biA = n; }
        if (vB > bestB) { bestB = vB; biB = n; }
    }
    int4* opA = (int4*)(out + (size_t)r0 * N_);
    int4* opB = (int4*)(out + (size_t)r1 * N_);
#pragma unroll
    for (int q = 0; q < 8; ++q) {
        int4 a, b;
        a.x = (q * 4 + 0) == biA; a.y = (q * 4 + 1) == biA;
        a.z = (q * 4 + 2) == biA; a.w = (q * 4 + 3) == biA;
        b.x = (q * 4 + 0) == biB; b.y = (q * 4 + 1) == biB;
        b.z = (q * 4 + 2) == biB; b.w = (q * 4 + 3) == biB;
        opA[q] = a; opB[q] = b;
    }
}

extern "C" void kernel_launch(void* const* d_in, const int* in_sizes, int n_in,
                              void* d_out, int out_size, void* d_ws, size_t ws_size,
                              hipStream_t stream) {
    const float* x    = (const float*)d_in[0];
    const int*   filt = (const int*)d_in[1];
    const float* w    = (const float*)d_in[2];
    int* out = (int*)d_out;

    char* ws = (char*)d_ws;
    float* raw  = (float*)ws;                          // 1 MB (256*32*32 fp32)
    float* fam  = (float*)(ws + (1 << 20));            // 4 B
    float* S    = (float*)(ws + (1 << 20) + 128);      // 1 KB
    float* part = (float*)(ws + (2u << 20));           // 64 MB split-K partials

    const size_t need = (2u << 20) + (size_t)NCH * (BATCH * C_ * N_) * sizeof(float);
    const int use_part = (ws_size >= need) ? 1 : 0;

    if (use_part) {
        hipMemsetAsync(ws + (1 << 20), 0, 128, stream);          // fam only
    } else {
        hipMemsetAsync(ws, 0, (1 << 20) + 128, stream);          // raw + fam (atomic path)
    }
    hipLaunchKernelGGL(k_sum,    dim3(256), dim3(256), 0, stream, x, filt, S);
    hipLaunchKernelGGL(k_gemm,   dim3(512), dim3(512), 0, stream, x, filt, w, part, raw, use_part);
    if (use_part)
        hipLaunchKernelGGL(k_reduce, dim3(256), dim3(256), 0, stream, part, raw);
    hipLaunchKernelGGL(k_fam,    dim3(32),  dim3(256), 0, stream, raw, S, fam);
    hipLaunchKernelGGL(k_sample, dim3(16),  dim3(256), 0, stream, raw, S, fam, out);
}

// Round 2
// 280.727 us; speedup vs baseline: 1.3920x; 1.3920x over previous
//
// R9: k_gemm = R7 body verbatim (proven 106us, no spills), ONLY the epilogue
// changed: plain stores to split-K partials part[chunk] (+k_reduce) instead of
// 16.8M 64-way-contended atomicAdd RMWs. k_reduce fused with familiarity
// reduction (k_fam kept only for the atomic fallback path when ws is small).
// k_sum / k_sample / PRNG byte-identical to R7.
#include <hip/hip_runtime.h>
#include <stdint.h>

#define BATCH 256
#define NMAC  512
#define ROWF  128            // cms_prev * neur_prev
#define I_    32768
#define C_    32
#define N_    32
#define XROW  (NMAC * ROWF)  // 65536 floats per batch row
#define NCH   64             // split-K chunks (512 i each)

typedef float  f32x4  __attribute__((ext_vector_type(4)));
typedef __bf16 bf16x8 __attribute__((ext_vector_type(8)));

__device__ __forceinline__ uint32_t f2bf_rne(float f) {
    uint32_t u = __builtin_bit_cast(uint32_t, f);
    return (u + 0x7FFFu + ((u >> 16) & 1u)) >> 16;
}

// ---------------- per-row sums S[b] (unchanged from R7) ----------------
__global__ __launch_bounds__(256) void k_sum(const float* __restrict__ x,
                                             const int* __restrict__ filt,
                                             float* __restrict__ S) {
    const int b = blockIdx.x;
    const int t = threadIdx.x;
    const float* xb = x + (size_t)b * XROW;
    float s = 0.f;
    for (int it = 0; it < 32; ++it) {
        int idx4 = it * 256 + t;           // 8192 float4 in gathered row
        int f = idx4 >> 5;
        int j4 = idx4 & 31;
        float4 v = *(const float4*)(xb + (size_t)filt[f] * ROWF + j4 * 4);
        s += v.x + v.y + v.z + v.w;
    }
    for (int o = 32; o > 0; o >>= 1) s += __shfl_down(s, o, 64);
    __shared__ float red[4];
    if ((t & 63) == 0) red[t >> 6] = s;
    __syncthreads();
    if (t == 0) S[b] = red[0] + red[1] + red[2] + red[3];
}

// ---------------- raw/part[b,c,n] = sum_i xg[b,i] * w[c,i,n] ----------------
// grid = 8 c-groups (4 c each) x 64 k-chunks (512 i each). 256 thr, 4 waves.
// KK=32 per stage: A tile 32 KB (split hi/lo bf16), W tile 8 KB -> 40 KB LDS.
// Structure identical to R7 (128 VGPR + acc in AGPRs, 2 blocks/CU). Epilogue:
// non-atomic stores into part[chunk] when use_part, else R7 atomic path.
__global__ __launch_bounds__(256, 2) void k_gemm(const float* __restrict__ x,
                                                 const int* __restrict__ filt,
                                                 const float* __restrict__ w,
                                                 float* __restrict__ part,
                                                 float* __restrict__ raw,
                                                 int use_part) {
    __shared__ __align__(16) unsigned short afr[32 * 512];  // 32 KB: 16 rt x 2 part
    __shared__ __align__(16) unsigned short wfr[8 * 512];   //  8 KB: 8 ct (c x n-half)

    const int t  = threadIdx.x;
    const int l  = t & 63;
    const int wv = t >> 6;
    const int chunk = blockIdx.x & 63;
    const int c0 = (blockIdx.x >> 6) * 4;

    f32x4 acc[4][8];
#pragma unroll
    for (int bt = 0; bt < 4; ++bt)
#pragma unroll
        for (int ct = 0; ct < 8; ++ct) acc[bt][ct] = f32x4{0.f, 0.f, 0.f, 0.f};

    // A staging map: thread covers (row = rr*32 + (t>>3), k = (t&7)*4 .. +3)
    const int ar     = t >> 3;             // 0..31
    const int ai     = t & 7;              // float4 slot: k = ai*4+e
    const int a_quad = ai >> 1;            // (ai*4)>>3
    const int a_j    = (ai & 1) * 4;
    // W staging map
    const int wn = t & 31;
    const int wc = t >> 5;                 // 0..7

    for (int st = 0; st < 16; ++st) {
        const int ifull = chunk * 512 + st * 32;
        const int fidx  = filt[ifull >> 7];
        const int ioff  = ifull & 127;     // 0,32,64,96 — all 32 i's in one filter row
        const float* xs = x + (size_t)fidx * ROWF + ioff;

        // ---- stage A: 32 KB fp32 -> split bf16 frag-order LDS ----
#pragma unroll
        for (int rr = 0; rr < 8; ++rr) {
            int row = rr * 32 + ar;
            float4 v = *(const float4*)(xs + (size_t)row * XROW + ai * 4);
            uint32_t u0 = __builtin_bit_cast(uint32_t, v.x);
            uint32_t u1 = __builtin_bit_cast(uint32_t, v.y);
            uint32_t u2 = __builtin_bit_cast(uint32_t, v.z);
            uint32_t u3 = __builtin_bit_cast(uint32_t, v.w);
            // hi = truncate-to-bf16 (error absorbed by lo); lo = RNE bf16 of remainder
            float l0 = v.x - __builtin_bit_cast(float, u0 & 0xFFFF0000u);
            float l1 = v.y - __builtin_bit_cast(float, u1 & 0xFFFF0000u);
            float l2 = v.z - __builtin_bit_cast(float, u2 & 0xFFFF0000u);
            float l3 = v.w - __builtin_bit_cast(float, u3 & 0xFFFF0000u);
            uint2 hp, lp;
            hp.x = (u0 >> 16) | (u1 & 0xFFFF0000u);
            hp.y = (u2 >> 16) | (u3 & 0xFFFF0000u);
            lp.x = f2bf_rne(l0) | (f2bf_rne(l1) << 16);
            lp.y = f2bf_rne(l2) | (f2bf_rne(l3) << 16);
            int rt   = row >> 4;
            int lane = a_quad * 16 + (row & 15);
            int base = (rt * 2) * 512 + lane * 8 + a_j;
            *(uint2*)&afr[base]       = hp;          // part 0 (hi)
            *(uint2*)&afr[base + 512] = lp;          // part 1 (lo)
        }

        // ---- stage W: k-pair scalar loads, pack top-16s ({0,1} exact), frag order ----
#pragma unroll
        for (int q = 0; q < 8; ++q) {
            int sl  = wc + 8 * q;                    // 0..63 = (c, il-pair)
            int c   = sl >> 4;
            int il  = (sl & 15) * 2;                 // even k in [0,32)
            const float* wp = w + ((size_t)(c0 + c) * I_ + ifull + il) * N_ + wn;
            uint32_t u0 = __builtin_bit_cast(uint32_t, wp[0]);
            uint32_t u1 = __builtin_bit_cast(uint32_t, wp[N_]);
            uint32_t pk = (u0 >> 16) | (u1 & 0xFFFF0000u);
            int lane = (il >> 3) * 16 + (wn & 15);
            int ct   = c * 2 + (wn >> 4);
            *(uint32_t*)&wfr[ct * 512 + lane * 8 + (il & 7)] = pk;
        }
        __syncthreads();

        // ---- MFMA: 4 row-tiles x 8 (c,n)-tiles x 2 parts ----
        bf16x8 av[4][2];
#pragma unroll
        for (int bt = 0; bt < 4; ++bt)
#pragma unroll
            for (int p = 0; p < 2; ++p)
                av[bt][p] = *(const bf16x8*)&afr[((wv * 4 + bt) * 2 + p) * 512 + l * 8];
        bf16x8 bv[8];
#pragma unroll
        for (int ct = 0; ct < 8; ++ct)
            bv[ct] = *(const bf16x8*)&wfr[ct * 512 + l * 8];
#pragma unroll
        for (int bt = 0; bt < 4; ++bt)
#pragma unroll
            for (int ct = 0; ct < 8; ++ct) {
                acc[bt][ct] = __builtin_amdgcn_mfma_f32_16x16x32_bf16(av[bt][0], bv[ct], acc[bt][ct], 0, 0, 0);
                acc[bt][ct] = __builtin_amdgcn_mfma_f32_16x16x32_bf16(av[bt][1], bv[ct], acc[bt][ct], 0, 0, 0);
            }
        __syncthreads();
    }

    // ---- epilogue: D col = lane&15, row = (lane>>4)*4 + reg ----
    const int quad = l >> 4, n15 = l & 15;
    if (use_part) {
        float* dst = part + (size_t)chunk * (BATCH * C_ * N_);
#pragma unroll
        for (int bt = 0; bt < 4; ++bt) {
#pragma unroll
            for (int ct = 0; ct < 8; ++ct) {
                int c = c0 + (ct >> 1);
                int n = (ct & 1) * 16 + n15;
#pragma unroll
                for (int r = 0; r < 4; ++r) {
                    int b = (wv * 4 + bt) * 16 + quad * 4 + r;
                    dst[((size_t)b * C_ + c) * N_ + n] = acc[bt][ct][r];
                }
            }
        }
    } else {
#pragma unroll
        for (int bt = 0; bt < 4; ++bt) {
#pragma unroll
            for (int ct = 0; ct < 8; ++ct) {
                int c = c0 + (ct >> 1);
                int n = (ct & 1) * 16 + n15;
#pragma unroll
                for (int r = 0; r < 4; ++r) {
                    int b = (wv * 4 + bt) * 16 + quad * 4 + r;
                    atomicAdd(&raw[((size_t)b * C_ + c) * N_ + n], acc[bt][ct][r]);
                }
            }
        }
    }
}

// ---------------- split-K reduce + fused familiarity ----------------
// raw = sum_ch part[ch]; fam += max_n(raw)/S per (b,c) row (8 float4 per row).
__global__ __launch_bounds__(256) void k_reduce(const float* __restrict__ part,
                                                const float* __restrict__ S,
                                                float* __restrict__ raw,
                                                float* __restrict__ fam) {
    const int i4 = blockIdx.x * 256 + threadIdx.x;     // 65536 float4
    const f32x4* p = (const f32x4*)part;
    f32x4 s = f32x4{0.f, 0.f, 0.f, 0.f};
#pragma unroll 8
    for (int ch = 0; ch < NCH; ++ch) s += p[(size_t)ch * 65536 + i4];
    ((f32x4*)raw)[i4] = s;
    // row r = i4>>3 spans lanes (q = i4&7); max over n then /S, sum into fam
    float m = fmaxf(fmaxf(s[0], s[1]), fmaxf(s[2], s[3]));
    m = fmaxf(m, __shfl_xor(m, 1, 64));
    m = fmaxf(m, __shfl_xor(m, 2, 64));
    m = fmaxf(m, __shfl_xor(m, 4, 64));
    int r = i4 >> 3;
    float v = ((i4 & 7) == 0) ? (m / S[r >> 5]) : 0.f;  // divide after max: monotone-exact
    for (int o = 32; o > 0; o >>= 1) v += __shfl_down(v, o, 64);
    __shared__ float red[4];
    if ((threadIdx.x & 63) == 0) red[threadIdx.x >> 6] = v;
    __syncthreads();
    if (threadIdx.x == 0) atomicAdd(fam, red[0] + red[1] + red[2] + red[3]);
}

// ---------------- familiarity (fallback path only, unchanged) ----------------
__global__ __launch_bounds__(256) void k_fam(const float* __restrict__ raw,
                                             const float* __restrict__ S,
                                             float* __restrict__ fam) {
    int r = blockIdx.x * 256 + threadIdx.x;            // 8192 rows
    const float4* ap = (const float4*)(raw + (size_t)r * N_);
    float m = -3.0e38f;
#pragma unroll
    for (int q = 0; q < 8; ++q) {
        float4 v = ap[q];
        m = fmaxf(m, fmaxf(fmaxf(v.x, v.y), fmaxf(v.z, v.w)));
    }
    m = m / S[r >> 5];                                 // divide after max: monotone-exact
    for (int o = 32; o > 0; o >>= 1) m += __shfl_down(m, o, 64);
    __shared__ float red[4];
    if ((threadIdx.x & 63) == 0) red[threadIdx.x >> 6] = m;
    __syncthreads();
    if (threadIdx.x == 0) atomicAdd(fam, red[0] + red[1] + red[2] + red[3]);
}

// ---------------- Threefry-2x32-20 core (unchanged) ----------------
__device__ __forceinline__ uint32_t rotl32(uint32_t x, uint32_t r) {
    return (x << r) | (x >> (32u - r));
}
__device__ __forceinline__ void threefry(uint32_t k0, uint32_t k1,
                                         uint32_t x0, uint32_t x1,
                                         uint32_t& o0, uint32_t& o1) {
    uint32_t ks2 = k0 ^ k1 ^ 0x1BD11BDAu;
    x0 += k0; x1 += k1;
    x0 += x1; x1 = rotl32(x1, 13); x1 ^= x0;
    x0 += x1; x1 = rotl32(x1, 15); x1 ^= x0;
    x0 += x1; x1 = rotl32(x1, 26); x1 ^= x0;
    x0 += x1; x1 = rotl32(x1, 6);  x1 ^= x0;
    x0 += k1; x1 += ks2 + 1u;
    x0 += x1; x1 = rotl32(x1, 17); x1 ^= x0;
    x0 += x1; x1 = rotl32(x1, 29); x1 ^= x0;
    x0 += x1; x1 = rotl32(x1, 16); x1 ^= x0;
    x0 += x1; x1 = rotl32(x1, 24); x1 ^= x0;
    x0 += ks2; x1 += k0 + 2u;
    x0 += x1; x1 = rotl32(x1, 13); x1 ^= x0;
    x0 += x1; x1 = rotl32(x1, 15); x1 ^= x0;
    x0 += x1; x1 = rotl32(x1, 26); x1 ^= x0;
    x0 += x1; x1 = rotl32(x1, 6);  x1 ^= x0;
    x0 += k0; x1 += k1 + 3u;
    x0 += x1; x1 = rotl32(x1, 17); x1 ^= x0;
    x0 += x1; x1 = rotl32(x1, 29); x1 ^= x0;
    x0 += x1; x1 = rotl32(x1, 16); x1 ^= x0;
    x0 += x1; x1 = rotl32(x1, 24); x1 ^= x0;
    x0 += k1; x1 += ks2 + 4u;
    x0 += x1; x1 = rotl32(x1, 13); x1 ^= x0;
    x0 += x1; x1 = rotl32(x1, 15); x1 ^= x0;
    x0 += x1; x1 = rotl32(x1, 26); x1 ^= x0;
    x0 += x1; x1 = rotl32(x1, 6);  x1 ^= x0;
    x0 += ks2; x1 += k0 + 5u;
    o0 = x0; o1 = x1;
}

__device__ __forceinline__ float gumbel_of(uint32_t bits) {
    uint32_t fb = (bits >> 9) | 0x3F800000u;
    float f = __builtin_bit_cast(float, fb) - 1.0f;
    float u = f + 1.17549435e-38f;                     // == max(tiny, f*(1-tiny)+tiny)
    return -logf(-logf(u));
}

// ---------------- sample (unchanged: JAX partitionable threefry layout) ------
__global__ __launch_bounds__(256) void k_sample(const float* __restrict__ raw,
                                                const float* __restrict__ S,
                                                const float* __restrict__ fam,
                                                int* __restrict__ out) {
    int r0 = blockIdx.x * 256 + threadIdx.x;           // 0..4095
    int r1 = r0 + 4096;
    float avg  = fam[0] * (1.0f / 8192.0f);
    float temp = 1.0f / (avg + 1e-4f) - 1.0f;
    float sA = S[r0 >> 5], sB = S[r1 >> 5];
    const float* apA = raw + (size_t)r0 * N_;
    const float* apB = raw + (size_t)r1 * N_;

    float bestA = -3.4e38f, bestB = -3.4e38f;
    int biA = 0, biB = 0;
    for (int n = 0; n < 32; ++n) {
        uint32_t iA = (uint32_t)(r0 * 32 + n);
        uint32_t iB = (uint32_t)(r1 * 32 + n);
        uint32_t a0, a1, b0, b1;
        threefry(0u, 42u, 0u, iA, a0, a1);
        threefry(0u, 42u, 0u, iB, b0, b1);
        float vA = (apA[n] / sA) / temp + gumbel_of(a0 ^ a1);
        float vB = (apB[n] / sB) / temp + gumbel_of(b0 ^ b1);
        if (vA > bestA) { bestA = vA; biA = n; }
        if (vB > bestB) { bestB = vB; biB = n; }
    }
    int4* opA = (int4*)(out + (size_t)r0 * N_);
    int4* opB = (int4*)(out + (size_t)r1 * N_);
#pragma unroll
    for (int q = 0; q < 8; ++q) {
        int4 a, b;
        a.x = (q * 4 + 0) == biA; a.y = (q * 4 + 1) == biA;
        a.z = (q * 4 + 2) == biA; a.w = (q * 4 + 3) == biA;
        b.x = (q * 4 + 0) == biB; b.y = (q * 4 + 1) == biB;
        b.z = (q * 4 + 2) == biB; b.w = (q * 4 + 3) == biB;
        opA[q] = a; opB[q] = b;
    }
}

extern "C" void kernel_launch(void* const* d_in, const int* in_sizes, int n_in,
                              void* d_out, int out_size, void* d_ws, size_t ws_size,
                              hipStream_t stream) {
    const float* x    = (const float*)d_in[0];
    const int*   filt = (const int*)d_in[1];
    const float* w    = (const float*)d_in[2];
    int* out = (int*)d_out;

    char* ws = (char*)d_ws;
    float* raw  = (float*)ws;                          // 1 MB (256*32*32 fp32)
    float* fam  = (float*)(ws + (1 << 20));            // 4 B
    float* S    = (float*)(ws + (1 << 20) + 128);      // 1 KB
    float* part = (float*)(ws + (2u << 20));           // 64 MB split-K partials

    const size_t need = (2u << 20) + (size_t)NCH * (BATCH * C_ * N_) * sizeof(float);
    const int use_part = (ws_size >= need) ? 1 : 0;

    if (use_part) {
        hipMemsetAsync(ws + (1 << 20), 0, 128, stream);          // fam only
        hipLaunchKernelGGL(k_sum,    dim3(256), dim3(256), 0, stream, x, filt, S);
        hipLaunchKernelGGL(k_gemm,   dim3(512), dim3(256), 0, stream, x, filt, w, part, raw, 1);
        hipLaunchKernelGGL(k_reduce, dim3(256), dim3(256), 0, stream, part, S, raw, fam);
        hipLaunchKernelGGL(k_sample, dim3(16),  dim3(256), 0, stream, raw, S, fam, out);
    } else {
        hipMemsetAsync(ws, 0, (1 << 20) + 128, stream);          // raw + fam
        hipLaunchKernelGGL(k_sum,    dim3(256), dim3(256), 0, stream, x, filt, S);
        hipLaunchKernelGGL(k_gemm,   dim3(512), dim3(256), 0, stream, x, filt, w, part, raw, 0);
        hipLaunchKernelGGL(k_fam,    dim3(32),  dim3(256), 0, stream, raw, S, fam);
        hipLaunchKernelGGL(k_sample, dim3(16),  dim3(256), 0, stream, raw, S, fam, out);
    }
}